// Round 5
// baseline (1646.300 us; speedup 1.0000x reference)
//
#include <hip/hip_runtime.h>
#include <hip/hip_bf16.h>

// DeepLSTM on MI355X — v15: gate nonlinearity via LDS lerp-LUT (no trans ops
// in the hot loop).
//
// v14 post-mortem: 810us steady (predicted 780-810 — boundary theory
// confirmed). Counter arithmetic: VALUBusy(active)=41% -> 1400cy/SIMD/step
// of VALU-pipe work; only matches the op count if transcendentals cost
// ~16cy/wave64 (quarter-rate). Then trans alone = 2 waves x 40 ops x 16cy
// = 1280cy/SIMD/step = 38% of the period — the single largest bucket.
//
// v15: one 2049-entry tanh lerp-table over [-8,8] in LDS (8.2KB, built
// once from tanh_fast). tanh(x) = lut(x*128+1024); sigm(x) = 0.5 +
// 0.5*lut(x*64+1024) (sigm(x)=0.5+0.5*tanh(x/2), arg range +-16 covered).
// Each gate op: ~8 cheap VALU + ds_read2 on the (underused) LDS pipe,
// replacing 2 trans-unit ops (32cy of VALU-pipe). Lerp error <= 6e-6 —
// three orders below the bf16-h quantization noise that dominates absmax.
// Everything else byte-identical to v14.
//
// Grid: 32 blocks x 512 threads; block (l,g) = layer l, batch group g (16 rows).
// ws: [0,8KB) flags (prod@0, cons@4KB, 128B stride); [8KB,...) ring
//     [pair][RING_T][16][128] bf16.

#define T_ 512
#define L_ 8
#define H_ 128
#define G4_ 512
#define OUT_ 65
#define B_ 64
#define NG_ 4
#define BG_ 16
#define LDSW_ 136                          // padded LDS row stride (bf16)
#define HT_OFF_ (B_ * T_ * OUT_)           // 2129920
#define CT_OFF_ (HT_OFF_ + L_ * B_ * H_)   // 2195456
#define STEP_U64_ 512                      // one step's h-tile: 16x128 bf16 = 4KB

typedef __bf16 bf16_t;
typedef bf16_t bf16x8 __attribute__((ext_vector_type(8)));
typedef bf16_t bf16x4 __attribute__((ext_vector_type(4)));
typedef float f32x4 __attribute__((ext_vector_type(4)));
typedef unsigned long long u64;

union U128 { uint4 u; bf16x8 b; u64 d[2]; };

__device__ __forceinline__ float rcpf(float x) { return __builtin_amdgcn_rcpf(x); }
__device__ __forceinline__ float tanh_fast(float x) {
  const float e = __expf(-2.f * fabsf(x));
  const float r = 2.f * rcpf(1.f + e) - 1.f;
  return copysignf(r, x);
}
__device__ __forceinline__ int flag_ld(int* p) {
  return __hip_atomic_load(p, __ATOMIC_RELAXED, __HIP_MEMORY_SCOPE_AGENT);
}
__device__ __forceinline__ void flag_st(int* p, int v) {
  __hip_atomic_store(p, v, __ATOMIC_RELAXED, __HIP_MEMORY_SCOPE_AGENT);
}
__device__ __forceinline__ u64 ring_ld(const u64* p) {
  return __hip_atomic_load(const_cast<u64*>(p), __ATOMIC_RELAXED, __HIP_MEMORY_SCOPE_AGENT);
}
__device__ __forceinline__ void ring_st(u64* p, u64 v) {
  __hip_atomic_store(p, v, __ATOMIC_RELAXED, __HIP_MEMORY_SCOPE_AGENT);
}

__global__ void zero_flags(int* flags) { flags[blockIdx.x * 1024 + threadIdx.x] = 0; }

template <int SUB, int NSUB, int RING_T>
__global__ __launch_bounds__(512, 2)
void lstm_pipe(const int* __restrict__ xids, const float* __restrict__ embed,
               const float* __restrict__ wih_g, const float* __restrict__ bih_g,
               const float* __restrict__ whh_g, const float* __restrict__ bhh_g,
               const float* __restrict__ wout_g, const float* __restrict__ bout_g,
               float* __restrict__ out, int* __restrict__ flags,
               u64* __restrict__ ring) {
  constexpr int CTT = SUB * NSUB;  // steps per handoff boundary
  static_assert(RING_T >= 2 * CTT || RING_T >= T_, "need >=2 chunks of ring slack");
  static_assert((CTT & (CTT - 1)) == 0, "CTT power of 2");
  constexpr int NCH = T_ / CTT;
  const int l    = blockIdx.x >> 2;
  const int g    = blockIdx.x & 3;
  const int tid  = threadIdx.x;
  const int wv   = tid >> 6;      // wave 0..7: gate col-tiles {wv, wv+8, wv+16, wv+24}
  const int lane = tid & 63;
  const int q    = lane >> 4;     // quad 0..3
  const int col  = lane & 15;

  __shared__ __align__(16) bf16_t xchunk[CTT][16 * LDSW_];  // chunk input, A-layout
  __shared__ __align__(16) bf16_t hist[CTT][16 * LDSW_];    // circular h history
  __shared__ uint4 wout_lds[5][4][64];                      // L7 out-proj weights (20 KB)
  __shared__ float tanh_lut[2049];                          // tanh on [-8,8], 1/128 bins

  // ---- build the tanh lerp table (covered by the prologue barrier) ----
  for (int i = tid; i < 2049; i += 512) {
    const float x = (float)(i - 1024) * 0.0078125f;  // 1/128
    tanh_lut[i] = tanh_fast(x);
  }
  // lerp lookup: idxf pre-scaled by caller. ~8 cheap VALU + ds_read2, no trans.
  auto lutv = [&](float idxf) -> float {
    idxf = fminf(fmaxf(idxf, 0.f), 2047.f);
    const float fl = floorf(idxf);
    const int i0 = (int)fl;
    const float fr = idxf - fl;
    const float t0 = tanh_lut[i0];
    const float t1 = tanh_lut[i0 + 1];
    return fmaf(fr, t1 - t0, t0);
  };

  // ---- resident weight fragments (bf16, B-layout: lane holds B[k][n], n=col) ----
  U128 wih[4][4], whh[4][4];  // [gate-class c][k-tile kt]
#pragma unroll
  for (int c = 0; c < 4; ++c) {
    const int n = wv * 16 + c * 128 + col;
#pragma unroll
    for (int kt = 0; kt < 4; ++kt) {
      U128 a, b;
#pragma unroll
      for (int jj = 0; jj < 8; ++jj) {
        const int k = kt * 32 + q * 8 + jj;
        a.b[jj] = (bf16_t)wih_g[(l * H_ + k) * G4_ + n];
        b.b[jj] = (bf16_t)whh_g[(l * H_ + k) * G4_ + n];
      }
      wih[c][kt] = a;
      whh[c][kt] = b;
    }
  }
  // PIN the fragments: opaque to remat. 32-bit tied operands (128-bit
  // aggregates are unsupported: "tied indirect register inputs").
#pragma unroll
  for (int c = 0; c < 4; ++c)
#pragma unroll
    for (int kt = 0; kt < 4; ++kt) {
      asm volatile("" : "+v"(wih[c][kt].u.x), "+v"(wih[c][kt].u.y),
                        "+v"(wih[c][kt].u.z), "+v"(wih[c][kt].u.w));
      asm volatile("" : "+v"(whh[c][kt].u.x), "+v"(whh[c][kt].u.y),
                        "+v"(whh[c][kt].u.z), "+v"(whh[c][kt].u.w));
    }

  float bias[4];
#pragma unroll
  for (int c = 0; c < 4; ++c) {
    const int n = wv * 16 + c * 128 + col;
    bias[c] = bih_g[l * G4_ + n] + bhh_g[l * G4_ + n];
  }
  float bo = 0.f;
  const bool has_out = (l == L_ - 1) && (wv < 5);
  if (has_out) {
    const int n = wv * 16 + col;
#pragma unroll
    for (int kt = 0; kt < 4; ++kt) {
      U128 w;
#pragma unroll
      for (int jj = 0; jj < 8; ++jj) {
        const int k = kt * 32 + q * 8 + jj;
        w.b[jj] = (n < OUT_) ? (bf16_t)wout_g[k * OUT_ + n] : (bf16_t)(0.f);
      }
      wout_lds[wv][kt][lane] = w.u;  // stash in LDS, not registers
    }
    if (n < OUT_) bo = bout_g[n];
  }

  int* myprod   = flags + ((l * NG_ + g) << 5);
  int* prevprod = (l > 0) ? flags + (((l - 1) * NG_ + g) << 5) : flags;
  int* mycons   = flags + 1024 + ((l * NG_ + g) << 5);
  int* nextcons = (l < L_ - 1) ? flags + 1024 + (((l + 1) * NG_ + g) << 5) : flags;
  u64* myring  = (l < L_ - 1) ? ring + (size_t)(l * NG_ + g) * RING_T * STEP_U64_ : ring;
  const u64* srcring = (l > 0) ? ring + (size_t)((l - 1) * NG_ + g) * RING_T * STEP_U64_ : ring;

  const int aoff = col * LDSW_ + q * 8;  // A-fragment: m=lane&15, k=q*8+j
  float cst[4] = {0.f, 0.f, 0.f, 0.f};  // c-state: rows m=q*4+r, col j=16*wv+col
  int seen_prod = 0, seen_cons = 0;

  // ---- prologue: zero h_{-1} (hist[CTT-1]); acquire chunk 0 ----
  for (int i = tid; i < 16 * LDSW_; i += 512) hist[CTT - 1][i] = (bf16_t)(0.f);
  if (l == 0) {
    const int m  = tid >> 5;
    const int c4 = (tid & 31) << 2;
#pragma unroll
    for (int tl = 0; tl < CTT; ++tl) {
      const int token = xids[(g * BG_ + m) * T_ + tl];
      const float4 e = *(const float4*)(embed + token * H_ + c4);
      bf16x4 v;
      v[0] = (bf16_t)e.x; v[1] = (bf16_t)e.y; v[2] = (bf16_t)e.z; v[3] = (bf16_t)e.w;
      *(bf16x4*)(&xchunk[tl][m * LDSW_ + c4]) = v;
    }
  } else {
    if (tid == 0) {
      int v;
      do { v = flag_ld(prevprod); } while (v < CTT);
      seen_prod = v;
    }
    __syncthreads();
    const int idx = tid >> 2;
    if (idx < CTT * 16) {
      const int tl = idx >> 4, m = idx & 15, seg = tid & 3;
      const u64* src = srcring + (size_t)(tl & (RING_T - 1)) * STEP_U64_ + m * 32 + seg * 8;
      u64* dst = (u64*)(&xchunk[tl][m * LDSW_ + seg * 32]);
#pragma unroll
      for (int j = 0; j < 8; ++j) dst[j] = ring_ld(src + j);
    }
  }
  __syncthreads();  // hist[CTT-1] zeroed + xchunk(0) ready + wout_lds + lut ready

#pragma unroll 1
  for (int ch = 0; ch < NCH; ++ch) {
    const int tc0 = ch * CTT;

#pragma unroll
    for (int sub = 0; sub < NSUB; ++sub) {
      const int t0 = tc0 + sub * SUB;

      // ===== phase 1: dense x-half, gx[tl][c] = bias[c] + x_tl @ W_ih =====
      f32x4 gx[SUB][4];
#pragma unroll
      for (int tl = 0; tl < SUB; ++tl) {
        const int st = sub * SUB + tl;
        bf16x8 xa[4];
#pragma unroll
        for (int kt = 0; kt < 4; ++kt)
          xa[kt] = *(const bf16x8*)(&xchunk[st][aoff + kt * 32]);
#pragma unroll
        for (int c = 0; c < 4; ++c) {
          f32x4 a = (f32x4){bias[c], bias[c], bias[c], bias[c]};
#pragma unroll
          for (int kt = 0; kt < 4; ++kt)
            a = __builtin_amdgcn_mfma_f32_16x16x32_bf16(xa[kt], wih[c][kt].b, a, 0, 0, 0);
          gx[tl][c] = a;
        }
      }

      // ===== phase 2: SUB recurrent steps, 1 clean barrier each =====
#pragma unroll
      for (int tl = 0; tl < SUB; ++tl) {
        const int st = sub * SUB + tl;
        bf16x8 ha[4];
#pragma unroll
        for (int kt = 0; kt < 4; ++kt)
          ha[kt] = *(const bf16x8*)(&hist[(st + CTT - 1) & (CTT - 1)][aoff + kt * 32]);
#pragma unroll
        for (int c = 0; c < 4; ++c)
#pragma unroll
          for (int kt = 0; kt < 4; ++kt)
            gx[tl][c] = __builtin_amdgcn_mfma_f32_16x16x32_bf16(ha[kt], whh[c][kt].b, gx[tl][c], 0, 0, 0);

        float hv[4];
        bf16_t hb[4];
#pragma unroll
        for (int r = 0; r < 4; ++r) {
          const float iv = fmaf(lutv(fmaf(gx[tl][0][r], 64.f, 1024.f)), 0.5f, 0.5f);
          const float fv = fmaf(lutv(fmaf(gx[tl][1][r], 64.f, 1024.f)), 0.5f, 0.5f);
          const float gv = lutv(fmaf(gx[tl][2][r], 128.f, 1024.f));
          const float ov = fmaf(lutv(fmaf(gx[tl][3][r], 64.f, 1024.f)), 0.5f, 0.5f);
          const float cv = fv * cst[r] + iv * gv;
          cst[r] = cv;
          const float h = ov * lutv(fmaf(cv, 128.f, 1024.f));
          hv[r] = h;
          hb[r] = (bf16_t)h;
        }
        {
          const int jc = wv * 16 + col;
#pragma unroll
          for (int r = 0; r < 4; ++r)
            hist[st][(q * 4 + r) * LDSW_ + jc] = hb[r];
        }
        if (t0 + tl == T_ - 1) {  // final hT / cT
          const int jc = wv * 16 + col;
#pragma unroll
          for (int r = 0; r < 4; ++r) {
            const int b = g * BG_ + q * 4 + r;
            out[HT_OFF_ + (l * B_ + b) * H_ + jc] = hv[r];
            out[CT_OFF_ + (l * B_ + b) * H_ + jc] = cst[r];
          }
        }
        __syncthreads();  // hist[st] published block-wide
      }
    }

    // ===== L7: batched out-projection from hist (whole super-chunk) =====
    if (has_out) {
      const int n = wv * 16 + col;
#pragma unroll
      for (int st = 0; st < CTT; ++st) {
        f32x4 oacc = (f32x4){0.f, 0.f, 0.f, 0.f};
#pragma unroll
        for (int kt = 0; kt < 4; ++kt) {
          U128 w;
          w.u = wout_lds[wv][kt][lane];
          const bf16x8 a = *(const bf16x8*)(&hist[st][col * LDSW_ + kt * 32 + q * 8]);
          oacc = __builtin_amdgcn_mfma_f32_16x16x32_bf16(a, w.b, oacc, 0, 0, 0);
        }
        if (n < OUT_) {
#pragma unroll
          for (int r = 0; r < 4; ++r) {
            const int b = g * BG_ + q * 4 + r;
            out[(b * T_ + (tc0 + st)) * OUT_ + n] = oacc[r] + bo;
          }
        }
      }
    }

    // ===== boundary: batched ring stores + poll (overlapped) + publish + acquire =====
    if (ch + 1 < NCH) {
      if (l < L_ - 1) {  // whole super-chunk's h-tiles; drain overlaps tid0's poll
#pragma unroll
        for (int st = 0; st < CTT; ++st) {
          const u64 val = *(const u64*)(&hist[st][(tid >> 5) * LDSW_ + ((tid & 31) << 2)]);
          ring_st(&myring[(size_t)((tc0 + st) & (RING_T - 1)) * STEP_U64_ + tid], val);
        }
      }
      if (tid == 0) {
        if (RING_T < T_ && l > 0) flag_st(mycons, tc0 + CTT);  // BEFORE polls (no deadlock)
        if (l > 0) {
          const int target = tc0 + 2 * CTT;
          if (seen_prod < target) {
            int v;
            do { v = flag_ld(prevprod); } while (v < target);
            seen_prod = v;
          }
        }
        if (RING_T < T_ && l < L_ - 1 && tc0 + 2 * CTT > RING_T) {
          const int need = tc0 + 2 * CTT - RING_T;
          if (seen_cons < need) {
            int v;
            do { v = flag_ld(nextcons); } while (v < need);
            seen_cons = v;
          }
        }
      }
      __syncthreads();  // drains ring stores (per-wave vmcnt); gates polls
      if (l < L_ - 1 && tid == 0) {
        flag_st(myprod, tc0 + CTT);  // sc1 stores already at coherence point
      }
      if (l == 0) {
        const int m  = tid >> 5;
        const int c4 = (tid & 31) << 2;
#pragma unroll
        for (int tl = 0; tl < CTT; ++tl) {
          const int token = xids[(g * BG_ + m) * T_ + tc0 + CTT + tl];
          const float4 e = *(const float4*)(embed + token * H_ + c4);
          bf16x4 v;
          v[0] = (bf16_t)e.x; v[1] = (bf16_t)e.y; v[2] = (bf16_t)e.z; v[3] = (bf16_t)e.w;
          *(bf16x4*)(&xchunk[tl][m * LDSW_ + c4]) = v;
        }
      } else {
        const int idx = tid >> 2;
        if (idx < CTT * 16) {
          const int tl = idx >> 4, m = idx & 15, seg = tid & 3;
          const u64* src = srcring + (size_t)((tc0 + CTT + tl) & (RING_T - 1)) * STEP_U64_ + m * 32 + seg * 8;
          u64* dst = (u64*)(&xchunk[tl][m * LDSW_ + seg * 32]);
#pragma unroll
          for (int j = 0; j < 8; ++j) dst[j] = ring_ld(src + j);
        }
      }
      __syncthreads();  // xchunk(ch+1) ready
    } else if (l < L_ - 1) {
      // final chunk: batched stores, drain, publish T_
#pragma unroll
      for (int st = 0; st < CTT; ++st) {
        const u64 val = *(const u64*)(&hist[st][(tid >> 5) * LDSW_ + ((tid & 31) << 2)]);
        ring_st(&myring[(size_t)((tc0 + st) & (RING_T - 1)) * STEP_U64_ + tid], val);
      }
      __syncthreads();  // drain last chunk's ring stores
      if (tid == 0) {
        flag_st(myprod, T_);
      }
    }
  }
}

extern "C" void kernel_launch(void* const* d_in, const int* in_sizes, int n_in,
                              void* d_out, int out_size, void* d_ws, size_t ws_size,
                              hipStream_t stream) {
  (void)in_sizes; (void)n_in; (void)out_size;
  const int*   x     = (const int*)d_in[0];
  const float* embed = (const float*)d_in[1];
  const float* w_ih  = (const float*)d_in[2];
  const float* b_ih  = (const float*)d_in[3];
  const float* w_hh  = (const float*)d_in[4];
  const float* b_hh  = (const float*)d_in[5];
  const float* w_out = (const float*)d_in[6];
  const float* b_out = (const float*)d_in[7];
  float* out = (float*)d_out;

  int* flags = (int*)d_ws;                     // 8 KB: prod@0, cons@4KB
  u64* ring  = (u64*)((char*)d_ws + 8192);

  hipLaunchKernelGGL(zero_flags, dim3(2), dim3(1024), 0, stream, flags);

  auto need = [&](int ring_t) { return (size_t)8192 + (size_t)28 * ring_t * 4096; };

  if (ws_size >= need(512)) {        // 57 MB: full history, no back-pressure
    hipLaunchKernelGGL((lstm_pipe<4, 2, 512>), dim3(L_ * NG_), dim3(512), 0, stream,
                       x, embed, w_ih, b_ih, w_hh, b_hh, w_out, b_out, out, flags, ring);
  } else if (ws_size >= need(16)) {  // 1.8 MB
    hipLaunchKernelGGL((lstm_pipe<4, 2, 16>), dim3(L_ * NG_), dim3(512), 0, stream,
                       x, embed, w_ih, b_ih, w_hh, b_hh, w_out, b_out, out, flags, ring);
  } else if (ws_size >= need(8)) {   // 0.92 MB
    hipLaunchKernelGGL((lstm_pipe<4, 1, 8>), dim3(L_ * NG_), dim3(512), 0, stream,
                       x, embed, w_ih, b_ih, w_hh, b_hh, w_out, b_out, out, flags, ring);
  } else {                           // 0.47 MB worst case
    hipLaunchKernelGGL((lstm_pipe<2, 1, 4>), dim3(L_ * NG_), dim3(512), 0, stream,
                       x, embed, w_ih, b_ih, w_hh, b_hh, w_out, b_out, out, flags, ring);
  }
}

// Round 6
// 1490.291 us; speedup vs baseline: 1.1047x; 1.1047x over previous
//
#include <hip/hip_runtime.h>
#include <hip/hip_bf16.h>

// DeepLSTM on MI355X — v16: actually make W_hh register-resident.
//
// v15 post-mortem (1595us, 2x regression): LDS LUT put a conflict-serialized
// dependent ds_read chain on the step critical path — reverted entirely.
//
// The real finding is in v14's counters: absolute VALU issue is
// ~1400cy/SIMD/step but the visible gate+support code is only ~500cy.
// VGPR_Count=128 vs ~240 of declared state => the weight fragments are NOT
// resident; the one-shot asm pin only forces liveness at the pin point,
// then the allocator remats. Every step each wave rebuilds 16 whh
// fragments from global (8 f32 loads + cvt + pack each ~ 300 instrs) with
// an L2-latency chain in front of the recurrent MFMAs — the missing VALU.
//
// v16 = v14 numerics byte-identical, register strategy changed:
//  (a) wih pins DELETED — wih is phase-1-only (off the h-dependency chain);
//      let it remat there. Frees ~64 regs of demand.
//  (b) whh pinned at the top of EVERY sub-chunk iteration (unrolled), so
//      the 16 fragments are live-in registers throughout; per-step remat
//      is never profitable. Demand ~ whh(64)+gx(64)+ha(16)+misc(~50) ~ 195.
// Verification: VGPR_Count must jump 128 -> ~190+.
//
// Grid: 32 blocks x 512 threads; block (l,g) = layer l, batch group g (16 rows).
// ws: [0,8KB) flags (prod@0, cons@4KB, 128B stride); [8KB,...) ring
//     [pair][RING_T][16][128] bf16.

#define T_ 512
#define L_ 8
#define H_ 128
#define G4_ 512
#define OUT_ 65
#define B_ 64
#define NG_ 4
#define BG_ 16
#define LDSW_ 136                          // padded LDS row stride (bf16)
#define HT_OFF_ (B_ * T_ * OUT_)           // 2129920
#define CT_OFF_ (HT_OFF_ + L_ * B_ * H_)   // 2195456
#define STEP_U64_ 512                      // one step's h-tile: 16x128 bf16 = 4KB

typedef __bf16 bf16_t;
typedef bf16_t bf16x8 __attribute__((ext_vector_type(8)));
typedef bf16_t bf16x4 __attribute__((ext_vector_type(4)));
typedef float f32x4 __attribute__((ext_vector_type(4)));
typedef unsigned long long u64;

union U128 { uint4 u; bf16x8 b; u64 d[2]; };

__device__ __forceinline__ float rcpf(float x) { return __builtin_amdgcn_rcpf(x); }
__device__ __forceinline__ float sigm(float x) { return rcpf(1.f + __expf(-x)); }
__device__ __forceinline__ float tanh_fast(float x) {
  const float e = __expf(-2.f * fabsf(x));
  const float r = 2.f * rcpf(1.f + e) - 1.f;
  return copysignf(r, x);
}
__device__ __forceinline__ int flag_ld(int* p) {
  return __hip_atomic_load(p, __ATOMIC_RELAXED, __HIP_MEMORY_SCOPE_AGENT);
}
__device__ __forceinline__ void flag_st(int* p, int v) {
  __hip_atomic_store(p, v, __ATOMIC_RELAXED, __HIP_MEMORY_SCOPE_AGENT);
}
__device__ __forceinline__ u64 ring_ld(const u64* p) {
  return __hip_atomic_load(const_cast<u64*>(p), __ATOMIC_RELAXED, __HIP_MEMORY_SCOPE_AGENT);
}
__device__ __forceinline__ void ring_st(u64* p, u64 v) {
  __hip_atomic_store(p, v, __ATOMIC_RELAXED, __HIP_MEMORY_SCOPE_AGENT);
}

__global__ void zero_flags(int* flags) { flags[blockIdx.x * 1024 + threadIdx.x] = 0; }

template <int SUB, int NSUB, int RING_T>
__global__ __launch_bounds__(512, 2)
void lstm_pipe(const int* __restrict__ xids, const float* __restrict__ embed,
               const float* __restrict__ wih_g, const float* __restrict__ bih_g,
               const float* __restrict__ whh_g, const float* __restrict__ bhh_g,
               const float* __restrict__ wout_g, const float* __restrict__ bout_g,
               float* __restrict__ out, int* __restrict__ flags,
               u64* __restrict__ ring) {
  constexpr int CTT = SUB * NSUB;  // steps per handoff boundary
  static_assert(RING_T >= 2 * CTT || RING_T >= T_, "need >=2 chunks of ring slack");
  static_assert((CTT & (CTT - 1)) == 0, "CTT power of 2");
  constexpr int NCH = T_ / CTT;
  const int l    = blockIdx.x >> 2;
  const int g    = blockIdx.x & 3;
  const int tid  = threadIdx.x;
  const int wv   = tid >> 6;      // wave 0..7: gate col-tiles {wv, wv+8, wv+16, wv+24}
  const int lane = tid & 63;
  const int q    = lane >> 4;     // quad 0..3
  const int col  = lane & 15;

  __shared__ __align__(16) bf16_t xchunk[CTT][16 * LDSW_];  // chunk input, A-layout
  __shared__ __align__(16) bf16_t hist[CTT][16 * LDSW_];    // circular h history
  __shared__ uint4 wout_lds[5][4][64];                      // L7 out-proj weights (20 KB)

  // ---- weight fragments (bf16, B-layout: lane holds B[k][n], n=col) ----
  // whh: must be register-resident (on the per-step critical path).
  // wih: phase-1 only — NOT pinned; the allocator may remat it there.
  U128 wih[4][4], whh[4][4];  // [gate-class c][k-tile kt]
#pragma unroll
  for (int c = 0; c < 4; ++c) {
    const int n = wv * 16 + c * 128 + col;
#pragma unroll
    for (int kt = 0; kt < 4; ++kt) {
      U128 a, b;
#pragma unroll
      for (int jj = 0; jj < 8; ++jj) {
        const int k = kt * 32 + q * 8 + jj;
        a.b[jj] = (bf16_t)wih_g[(l * H_ + k) * G4_ + n];
        b.b[jj] = (bf16_t)whh_g[(l * H_ + k) * G4_ + n];
      }
      wih[c][kt] = a;
      whh[c][kt] = b;
    }
  }
#define PIN_WHH()                                                         \
  _Pragma("unroll") for (int pc = 0; pc < 4; ++pc)                        \
  _Pragma("unroll") for (int pk = 0; pk < 4; ++pk) {                      \
    asm volatile("" : "+v"(whh[pc][pk].u.x), "+v"(whh[pc][pk].u.y),       \
                      "+v"(whh[pc][pk].u.z), "+v"(whh[pc][pk].u.w));      \
  }
  PIN_WHH();

  float bias[4];
#pragma unroll
  for (int c = 0; c < 4; ++c) {
    const int n = wv * 16 + c * 128 + col;
    bias[c] = bih_g[l * G4_ + n] + bhh_g[l * G4_ + n];
  }
  float bo = 0.f;
  const bool has_out = (l == L_ - 1) && (wv < 5);
  if (has_out) {
    const int n = wv * 16 + col;
#pragma unroll
    for (int kt = 0; kt < 4; ++kt) {
      U128 w;
#pragma unroll
      for (int jj = 0; jj < 8; ++jj) {
        const int k = kt * 32 + q * 8 + jj;
        w.b[jj] = (n < OUT_) ? (bf16_t)wout_g[k * OUT_ + n] : (bf16_t)(0.f);
      }
      wout_lds[wv][kt][lane] = w.u;  // stash in LDS, not registers
    }
    if (n < OUT_) bo = bout_g[n];
  }

  int* myprod   = flags + ((l * NG_ + g) << 5);
  int* prevprod = (l > 0) ? flags + (((l - 1) * NG_ + g) << 5) : flags;
  int* mycons   = flags + 1024 + ((l * NG_ + g) << 5);
  int* nextcons = (l < L_ - 1) ? flags + 1024 + (((l + 1) * NG_ + g) << 5) : flags;
  u64* myring  = (l < L_ - 1) ? ring + (size_t)(l * NG_ + g) * RING_T * STEP_U64_ : ring;
  const u64* srcring = (l > 0) ? ring + (size_t)((l - 1) * NG_ + g) * RING_T * STEP_U64_ : ring;

  const int aoff = col * LDSW_ + q * 8;  // A-fragment: m=lane&15, k=q*8+j
  float cst[4] = {0.f, 0.f, 0.f, 0.f};  // c-state: rows m=q*4+r, col j=16*wv+col
  int seen_prod = 0, seen_cons = 0;

  // ---- prologue: zero h_{-1} (hist[CTT-1]); acquire chunk 0 ----
  for (int i = tid; i < 16 * LDSW_; i += 512) hist[CTT - 1][i] = (bf16_t)(0.f);
  if (l == 0) {
    const int m  = tid >> 5;
    const int c4 = (tid & 31) << 2;
#pragma unroll
    for (int tl = 0; tl < CTT; ++tl) {
      const int token = xids[(g * BG_ + m) * T_ + tl];
      const float4 e = *(const float4*)(embed + token * H_ + c4);
      bf16x4 v;
      v[0] = (bf16_t)e.x; v[1] = (bf16_t)e.y; v[2] = (bf16_t)e.z; v[3] = (bf16_t)e.w;
      *(bf16x4*)(&xchunk[tl][m * LDSW_ + c4]) = v;
    }
  } else {
    if (tid == 0) {
      int v;
      do { v = flag_ld(prevprod); } while (v < CTT);
      seen_prod = v;
    }
    __syncthreads();
    const int idx = tid >> 2;
    if (idx < CTT * 16) {
      const int tl = idx >> 4, m = idx & 15, seg = tid & 3;
      const u64* src = srcring + (size_t)(tl & (RING_T - 1)) * STEP_U64_ + m * 32 + seg * 8;
      u64* dst = (u64*)(&xchunk[tl][m * LDSW_ + seg * 32]);
#pragma unroll
      for (int j = 0; j < 8; ++j) dst[j] = ring_ld(src + j);
    }
  }
  __syncthreads();  // hist[CTT-1] zeroed + xchunk(0) ready + wout_lds ready

#pragma unroll 1
  for (int ch = 0; ch < NCH; ++ch) {
    const int tc0 = ch * CTT;

#pragma unroll
    for (int sub = 0; sub < NSUB; ++sub) {
      const int t0 = tc0 + sub * SUB;
      PIN_WHH();  // keep whh live-in registers across every sub-chunk

      // ===== phase 1: dense x-half, gx[tl][c] = bias[c] + x_tl @ W_ih =====
      f32x4 gx[SUB][4];
#pragma unroll
      for (int tl = 0; tl < SUB; ++tl) {
        const int st = sub * SUB + tl;
        bf16x8 xa[4];
#pragma unroll
        for (int kt = 0; kt < 4; ++kt)
          xa[kt] = *(const bf16x8*)(&xchunk[st][aoff + kt * 32]);
#pragma unroll
        for (int c = 0; c < 4; ++c) {
          f32x4 a = (f32x4){bias[c], bias[c], bias[c], bias[c]};
#pragma unroll
          for (int kt = 0; kt < 4; ++kt)
            a = __builtin_amdgcn_mfma_f32_16x16x32_bf16(xa[kt], wih[c][kt].b, a, 0, 0, 0);
          gx[tl][c] = a;
        }
      }

      // ===== phase 2: SUB recurrent steps, 1 clean barrier each =====
#pragma unroll
      for (int tl = 0; tl < SUB; ++tl) {
        const int st = sub * SUB + tl;
        bf16x8 ha[4];
#pragma unroll
        for (int kt = 0; kt < 4; ++kt)
          ha[kt] = *(const bf16x8*)(&hist[(st + CTT - 1) & (CTT - 1)][aoff + kt * 32]);
#pragma unroll
        for (int c = 0; c < 4; ++c)
#pragma unroll
          for (int kt = 0; kt < 4; ++kt)
            gx[tl][c] = __builtin_amdgcn_mfma_f32_16x16x32_bf16(ha[kt], whh[c][kt].b, gx[tl][c], 0, 0, 0);

        float hv[4];
        bf16_t hb[4];
#pragma unroll
        for (int r = 0; r < 4; ++r) {
          const float iv = sigm(gx[tl][0][r]);
          const float fv = sigm(gx[tl][1][r]);
          const float gv = tanh_fast(gx[tl][2][r]);
          const float ov = sigm(gx[tl][3][r]);
          const float cv = fv * cst[r] + iv * gv;
          cst[r] = cv;
          const float h = ov * tanh_fast(cv);
          hv[r] = h;
          hb[r] = (bf16_t)h;
        }
        {
          const int jc = wv * 16 + col;
#pragma unroll
          for (int r = 0; r < 4; ++r)
            hist[st][(q * 4 + r) * LDSW_ + jc] = hb[r];
        }
        if (t0 + tl == T_ - 1) {  // final hT / cT
          const int jc = wv * 16 + col;
#pragma unroll
          for (int r = 0; r < 4; ++r) {
            const int b = g * BG_ + q * 4 + r;
            out[HT_OFF_ + (l * B_ + b) * H_ + jc] = hv[r];
            out[CT_OFF_ + (l * B_ + b) * H_ + jc] = cst[r];
          }
        }
        __syncthreads();  // hist[st] published block-wide
      }
    }

    // ===== L7: batched out-projection from hist (whole super-chunk) =====
    if (has_out) {
      const int n = wv * 16 + col;
#pragma unroll
      for (int st = 0; st < CTT; ++st) {
        f32x4 oacc = (f32x4){0.f, 0.f, 0.f, 0.f};
#pragma unroll
        for (int kt = 0; kt < 4; ++kt) {
          U128 w;
          w.u = wout_lds[wv][kt][lane];
          const bf16x8 a = *(const bf16x8*)(&hist[st][col * LDSW_ + kt * 32 + q * 8]);
          oacc = __builtin_amdgcn_mfma_f32_16x16x32_bf16(a, w.b, oacc, 0, 0, 0);
        }
        if (n < OUT_) {
#pragma unroll
          for (int r = 0; r < 4; ++r) {
            const int b = g * BG_ + q * 4 + r;
            out[(b * T_ + (tc0 + st)) * OUT_ + n] = oacc[r] + bo;
          }
        }
      }
    }

    // ===== boundary: batched ring stores + poll (overlapped) + publish + acquire =====
    if (ch + 1 < NCH) {
      if (l < L_ - 1) {  // whole super-chunk's h-tiles; drain overlaps tid0's poll
#pragma unroll
        for (int st = 0; st < CTT; ++st) {
          const u64 val = *(const u64*)(&hist[st][(tid >> 5) * LDSW_ + ((tid & 31) << 2)]);
          ring_st(&myring[(size_t)((tc0 + st) & (RING_T - 1)) * STEP_U64_ + tid], val);
        }
      }
      if (tid == 0) {
        if (RING_T < T_ && l > 0) flag_st(mycons, tc0 + CTT);  // BEFORE polls (no deadlock)
        if (l > 0) {
          const int target = tc0 + 2 * CTT;
          if (seen_prod < target) {
            int v;
            do { v = flag_ld(prevprod); } while (v < target);
            seen_prod = v;
          }
        }
        if (RING_T < T_ && l < L_ - 1 && tc0 + 2 * CTT > RING_T) {
          const int need = tc0 + 2 * CTT - RING_T;
          if (seen_cons < need) {
            int v;
            do { v = flag_ld(nextcons); } while (v < need);
            seen_cons = v;
          }
        }
      }
      __syncthreads();  // drains ring stores (per-wave vmcnt); gates polls
      if (l < L_ - 1 && tid == 0) {
        flag_st(myprod, tc0 + CTT);  // sc1 stores already at coherence point
      }
      if (l == 0) {
        const int m  = tid >> 5;
        const int c4 = (tid & 31) << 2;
#pragma unroll
        for (int tl = 0; tl < CTT; ++tl) {
          const int token = xids[(g * BG_ + m) * T_ + tc0 + CTT + tl];
          const float4 e = *(const float4*)(embed + token * H_ + c4);
          bf16x4 v;
          v[0] = (bf16_t)e.x; v[1] = (bf16_t)e.y; v[2] = (bf16_t)e.z; v[3] = (bf16_t)e.w;
          *(bf16x4*)(&xchunk[tl][m * LDSW_ + c4]) = v;
        }
      } else {
        const int idx = tid >> 2;
        if (idx < CTT * 16) {
          const int tl = idx >> 4, m = idx & 15, seg = tid & 3;
          const u64* src = srcring + (size_t)((tc0 + CTT + tl) & (RING_T - 1)) * STEP_U64_ + m * 32 + seg * 8;
          u64* dst = (u64*)(&xchunk[tl][m * LDSW_ + seg * 32]);
#pragma unroll
          for (int j = 0; j < 8; ++j) dst[j] = ring_ld(src + j);
        }
      }
      __syncthreads();  // xchunk(ch+1) ready
    } else if (l < L_ - 1) {
      // final chunk: batched stores, drain, publish T_
#pragma unroll
      for (int st = 0; st < CTT; ++st) {
        const u64 val = *(const u64*)(&hist[st][(tid >> 5) * LDSW_ + ((tid & 31) << 2)]);
        ring_st(&myring[(size_t)((tc0 + st) & (RING_T - 1)) * STEP_U64_ + tid], val);
      }
      __syncthreads();  // drain last chunk's ring stores
      if (tid == 0) {
        flag_st(myprod, T_);
      }
    }
  }
#undef PIN_WHH
}

extern "C" void kernel_launch(void* const* d_in, const int* in_sizes, int n_in,
                              void* d_out, int out_size, void* d_ws, size_t ws_size,
                              hipStream_t stream) {
  (void)in_sizes; (void)n_in; (void)out_size;
  const int*   x     = (const int*)d_in[0];
  const float* embed = (const float*)d_in[1];
  const float* w_ih  = (const float*)d_in[2];
  const float* b_ih  = (const float*)d_in[3];
  const float* w_hh  = (const float*)d_in[4];
  const float* b_hh  = (const float*)d_in[5];
  const float* w_out = (const float*)d_in[6];
  const float* b_out = (const float*)d_in[7];
  float* out = (float*)d_out;

  int* flags = (int*)d_ws;                     // 8 KB: prod@0, cons@4KB
  u64* ring  = (u64*)((char*)d_ws + 8192);

  hipLaunchKernelGGL(zero_flags, dim3(2), dim3(1024), 0, stream, flags);

  auto need = [&](int ring_t) { return (size_t)8192 + (size_t)28 * ring_t * 4096; };

  if (ws_size >= need(512)) {        // 57 MB: full history, no back-pressure
    hipLaunchKernelGGL((lstm_pipe<4, 2, 512>), dim3(L_ * NG_), dim3(512), 0, stream,
                       x, embed, w_ih, b_ih, w_hh, b_hh, w_out, b_out, out, flags, ring);
  } else if (ws_size >= need(16)) {  // 1.8 MB
    hipLaunchKernelGGL((lstm_pipe<4, 2, 16>), dim3(L_ * NG_), dim3(512), 0, stream,
                       x, embed, w_ih, b_ih, w_hh, b_hh, w_out, b_out, out, flags, ring);
  } else if (ws_size >= need(8)) {   // 0.92 MB
    hipLaunchKernelGGL((lstm_pipe<4, 1, 8>), dim3(L_ * NG_), dim3(512), 0, stream,
                       x, embed, w_ih, b_ih, w_hh, b_hh, w_out, b_out, out, flags, ring);
  } else {                           // 0.47 MB worst case
    hipLaunchKernelGGL((lstm_pipe<2, 1, 4>), dim3(L_ * NG_), dim3(512), 0, stream,
                       x, embed, w_ih, b_ih, w_hh, b_hh, w_out, b_out, out, flags, ring);
  }
}

// Round 7
// 873.331 us; speedup vs baseline: 1.8851x; 1.7064x over previous
//
#include <hip/hip_runtime.h>
#include <hip/hip_bf16.h>

// DeepLSTM on MI355X — v17: v14 with the VGPR cap actually lifted.
//
// v16 post-mortem (1465us, VGPR still 128): in-loop pins made remat WORSE
// (FETCH 39->42GB). The real finding: VGPR_Count has been pinned at exactly
// 128 for six versions. __launch_bounds__(512, 2) — hipcc resolves this to
// 16 waves/CU (4 waves/SIMD) -> VGPR cap 128. The occupancy it protects is
// never used: grid = 32 blocks on 256 CUs, 1 block/CU max. The allocator
// has been FORCED to remat the weight fragments (the ~900cy/SIMD/step of
// unexplained VALU issue + L2 chains before the recurrent MFMAs).
//
// v17 = v14 byte-identical (810us steady, best so far) except
// __launch_bounds__(512, 1): cap -> 2 waves/SIMD @ 256 VGPR. Declared state
// whh(64)+wih(64)+gx(64)+ha(16)+misc(~30) ~ 240 now fits.
// Verification bit: VGPR_Count must jump 128 -> >=192.
//
// Grid: 32 blocks x 512 threads; block (l,g) = layer l, batch group g (16 rows).
// ws: [0,8KB) flags (prod@0, cons@4KB, 128B stride); [8KB,...) ring
//     [pair][RING_T][16][128] bf16.

#define T_ 512
#define L_ 8
#define H_ 128
#define G4_ 512
#define OUT_ 65
#define B_ 64
#define NG_ 4
#define BG_ 16
#define LDSW_ 136                          // padded LDS row stride (bf16)
#define HT_OFF_ (B_ * T_ * OUT_)           // 2129920
#define CT_OFF_ (HT_OFF_ + L_ * B_ * H_)   // 2195456
#define STEP_U64_ 512                      // one step's h-tile: 16x128 bf16 = 4KB

typedef __bf16 bf16_t;
typedef bf16_t bf16x8 __attribute__((ext_vector_type(8)));
typedef bf16_t bf16x4 __attribute__((ext_vector_type(4)));
typedef float f32x4 __attribute__((ext_vector_type(4)));
typedef unsigned long long u64;

union U128 { uint4 u; bf16x8 b; u64 d[2]; };

__device__ __forceinline__ float rcpf(float x) { return __builtin_amdgcn_rcpf(x); }
__device__ __forceinline__ float sigm(float x) { return rcpf(1.f + __expf(-x)); }
__device__ __forceinline__ float tanh_fast(float x) {
  const float e = __expf(-2.f * fabsf(x));
  const float r = 2.f * rcpf(1.f + e) - 1.f;
  return copysignf(r, x);
}
__device__ __forceinline__ int flag_ld(int* p) {
  return __hip_atomic_load(p, __ATOMIC_RELAXED, __HIP_MEMORY_SCOPE_AGENT);
}
__device__ __forceinline__ void flag_st(int* p, int v) {
  __hip_atomic_store(p, v, __ATOMIC_RELAXED, __HIP_MEMORY_SCOPE_AGENT);
}
__device__ __forceinline__ u64 ring_ld(const u64* p) {
  return __hip_atomic_load(const_cast<u64*>(p), __ATOMIC_RELAXED, __HIP_MEMORY_SCOPE_AGENT);
}
__device__ __forceinline__ void ring_st(u64* p, u64 v) {
  __hip_atomic_store(p, v, __ATOMIC_RELAXED, __HIP_MEMORY_SCOPE_AGENT);
}

__global__ void zero_flags(int* flags) { flags[blockIdx.x * 1024 + threadIdx.x] = 0; }

template <int SUB, int NSUB, int RING_T>
__global__ __launch_bounds__(512, 1)
void lstm_pipe(const int* __restrict__ xids, const float* __restrict__ embed,
               const float* __restrict__ wih_g, const float* __restrict__ bih_g,
               const float* __restrict__ whh_g, const float* __restrict__ bhh_g,
               const float* __restrict__ wout_g, const float* __restrict__ bout_g,
               float* __restrict__ out, int* __restrict__ flags,
               u64* __restrict__ ring) {
  constexpr int CTT = SUB * NSUB;  // steps per handoff boundary
  static_assert(RING_T >= 2 * CTT || RING_T >= T_, "need >=2 chunks of ring slack");
  static_assert((CTT & (CTT - 1)) == 0, "CTT power of 2");
  constexpr int NCH = T_ / CTT;
  const int l    = blockIdx.x >> 2;
  const int g    = blockIdx.x & 3;
  const int tid  = threadIdx.x;
  const int wv   = tid >> 6;      // wave 0..7: gate col-tiles {wv, wv+8, wv+16, wv+24}
  const int lane = tid & 63;
  const int q    = lane >> 4;     // quad 0..3
  const int col  = lane & 15;

  __shared__ __align__(16) bf16_t xchunk[CTT][16 * LDSW_];  // chunk input, A-layout
  __shared__ __align__(16) bf16_t hist[CTT][16 * LDSW_];    // circular h history
  __shared__ uint4 wout_lds[5][4][64];                      // L7 out-proj weights (20 KB)

  // ---- resident weight fragments (bf16, B-layout: lane holds B[k][n], n=col) ----
  U128 wih[4][4], whh[4][4];  // [gate-class c][k-tile kt]
#pragma unroll
  for (int c = 0; c < 4; ++c) {
    const int n = wv * 16 + c * 128 + col;
#pragma unroll
    for (int kt = 0; kt < 4; ++kt) {
      U128 a, b;
#pragma unroll
      for (int jj = 0; jj < 8; ++jj) {
        const int k = kt * 32 + q * 8 + jj;
        a.b[jj] = (bf16_t)wih_g[(l * H_ + k) * G4_ + n];
        b.b[jj] = (bf16_t)whh_g[(l * H_ + k) * G4_ + n];
      }
      wih[c][kt] = a;
      whh[c][kt] = b;
    }
  }
  // PIN the fragments: opaque to remat. 32-bit tied operands (128-bit
  // aggregates are unsupported: "tied indirect register inputs").
#pragma unroll
  for (int c = 0; c < 4; ++c)
#pragma unroll
    for (int kt = 0; kt < 4; ++kt) {
      asm volatile("" : "+v"(wih[c][kt].u.x), "+v"(wih[c][kt].u.y),
                        "+v"(wih[c][kt].u.z), "+v"(wih[c][kt].u.w));
      asm volatile("" : "+v"(whh[c][kt].u.x), "+v"(whh[c][kt].u.y),
                        "+v"(whh[c][kt].u.z), "+v"(whh[c][kt].u.w));
    }

  float bias[4];
#pragma unroll
  for (int c = 0; c < 4; ++c) {
    const int n = wv * 16 + c * 128 + col;
    bias[c] = bih_g[l * G4_ + n] + bhh_g[l * G4_ + n];
  }
  float bo = 0.f;
  const bool has_out = (l == L_ - 1) && (wv < 5);
  if (has_out) {
    const int n = wv * 16 + col;
#pragma unroll
    for (int kt = 0; kt < 4; ++kt) {
      U128 w;
#pragma unroll
      for (int jj = 0; jj < 8; ++jj) {
        const int k = kt * 32 + q * 8 + jj;
        w.b[jj] = (n < OUT_) ? (bf16_t)wout_g[k * OUT_ + n] : (bf16_t)(0.f);
      }
      wout_lds[wv][kt][lane] = w.u;  // stash in LDS, not registers
    }
    if (n < OUT_) bo = bout_g[n];
  }

  int* myprod   = flags + ((l * NG_ + g) << 5);
  int* prevprod = (l > 0) ? flags + (((l - 1) * NG_ + g) << 5) : flags;
  int* mycons   = flags + 1024 + ((l * NG_ + g) << 5);
  int* nextcons = (l < L_ - 1) ? flags + 1024 + (((l + 1) * NG_ + g) << 5) : flags;
  u64* myring  = (l < L_ - 1) ? ring + (size_t)(l * NG_ + g) * RING_T * STEP_U64_ : ring;
  const u64* srcring = (l > 0) ? ring + (size_t)((l - 1) * NG_ + g) * RING_T * STEP_U64_ : ring;

  const int aoff = col * LDSW_ + q * 8;  // A-fragment: m=lane&15, k=q*8+j
  float cst[4] = {0.f, 0.f, 0.f, 0.f};  // c-state: rows m=q*4+r, col j=16*wv+col
  int seen_prod = 0, seen_cons = 0;

  // ---- prologue: zero h_{-1} (hist[CTT-1]); acquire chunk 0 ----
  for (int i = tid; i < 16 * LDSW_; i += 512) hist[CTT - 1][i] = (bf16_t)(0.f);
  if (l == 0) {
    const int m  = tid >> 5;
    const int c4 = (tid & 31) << 2;
#pragma unroll
    for (int tl = 0; tl < CTT; ++tl) {
      const int token = xids[(g * BG_ + m) * T_ + tl];
      const float4 e = *(const float4*)(embed + token * H_ + c4);
      bf16x4 v;
      v[0] = (bf16_t)e.x; v[1] = (bf16_t)e.y; v[2] = (bf16_t)e.z; v[3] = (bf16_t)e.w;
      *(bf16x4*)(&xchunk[tl][m * LDSW_ + c4]) = v;
    }
  } else {
    if (tid == 0) {
      int v;
      do { v = flag_ld(prevprod); } while (v < CTT);
      seen_prod = v;
    }
    __syncthreads();
    const int idx = tid >> 2;
    if (idx < CTT * 16) {
      const int tl = idx >> 4, m = idx & 15, seg = tid & 3;
      const u64* src = srcring + (size_t)(tl & (RING_T - 1)) * STEP_U64_ + m * 32 + seg * 8;
      u64* dst = (u64*)(&xchunk[tl][m * LDSW_ + seg * 32]);
#pragma unroll
      for (int j = 0; j < 8; ++j) dst[j] = ring_ld(src + j);
    }
  }
  __syncthreads();  // hist[CTT-1] zeroed + xchunk(0) ready + wout_lds ready

#pragma unroll 1
  for (int ch = 0; ch < NCH; ++ch) {
    const int tc0 = ch * CTT;

#pragma unroll
    for (int sub = 0; sub < NSUB; ++sub) {
      const int t0 = tc0 + sub * SUB;

      // ===== phase 1: dense x-half, gx[tl][c] = bias[c] + x_tl @ W_ih =====
      f32x4 gx[SUB][4];
#pragma unroll
      for (int tl = 0; tl < SUB; ++tl) {
        const int st = sub * SUB + tl;
        bf16x8 xa[4];
#pragma unroll
        for (int kt = 0; kt < 4; ++kt)
          xa[kt] = *(const bf16x8*)(&xchunk[st][aoff + kt * 32]);
#pragma unroll
        for (int c = 0; c < 4; ++c) {
          f32x4 a = (f32x4){bias[c], bias[c], bias[c], bias[c]};
#pragma unroll
          for (int kt = 0; kt < 4; ++kt)
            a = __builtin_amdgcn_mfma_f32_16x16x32_bf16(xa[kt], wih[c][kt].b, a, 0, 0, 0);
          gx[tl][c] = a;
        }
      }

      // ===== phase 2: SUB recurrent steps, 1 clean barrier each =====
#pragma unroll
      for (int tl = 0; tl < SUB; ++tl) {
        const int st = sub * SUB + tl;
        bf16x8 ha[4];
#pragma unroll
        for (int kt = 0; kt < 4; ++kt)
          ha[kt] = *(const bf16x8*)(&hist[(st + CTT - 1) & (CTT - 1)][aoff + kt * 32]);
#pragma unroll
        for (int c = 0; c < 4; ++c)
#pragma unroll
          for (int kt = 0; kt < 4; ++kt)
            gx[tl][c] = __builtin_amdgcn_mfma_f32_16x16x32_bf16(ha[kt], whh[c][kt].b, gx[tl][c], 0, 0, 0);

        float hv[4];
        bf16_t hb[4];
#pragma unroll
        for (int r = 0; r < 4; ++r) {
          const float iv = sigm(gx[tl][0][r]);
          const float fv = sigm(gx[tl][1][r]);
          const float gv = tanh_fast(gx[tl][2][r]);
          const float ov = sigm(gx[tl][3][r]);
          const float cv = fv * cst[r] + iv * gv;
          cst[r] = cv;
          const float h = ov * tanh_fast(cv);
          hv[r] = h;
          hb[r] = (bf16_t)h;
        }
        {
          const int jc = wv * 16 + col;
#pragma unroll
          for (int r = 0; r < 4; ++r)
            hist[st][(q * 4 + r) * LDSW_ + jc] = hb[r];
        }
        if (t0 + tl == T_ - 1) {  // final hT / cT
          const int jc = wv * 16 + col;
#pragma unroll
          for (int r = 0; r < 4; ++r) {
            const int b = g * BG_ + q * 4 + r;
            out[HT_OFF_ + (l * B_ + b) * H_ + jc] = hv[r];
            out[CT_OFF_ + (l * B_ + b) * H_ + jc] = cst[r];
          }
        }
        __syncthreads();  // hist[st] published block-wide
      }
    }

    // ===== L7: batched out-projection from hist (whole super-chunk) =====
    if (has_out) {
      const int n = wv * 16 + col;
#pragma unroll
      for (int st = 0; st < CTT; ++st) {
        f32x4 oacc = (f32x4){0.f, 0.f, 0.f, 0.f};
#pragma unroll
        for (int kt = 0; kt < 4; ++kt) {
          U128 w;
          w.u = wout_lds[wv][kt][lane];
          const bf16x8 a = *(const bf16x8*)(&hist[st][col * LDSW_ + kt * 32 + q * 8]);
          oacc = __builtin_amdgcn_mfma_f32_16x16x32_bf16(a, w.b, oacc, 0, 0, 0);
        }
        if (n < OUT_) {
#pragma unroll
          for (int r = 0; r < 4; ++r) {
            const int b = g * BG_ + q * 4 + r;
            out[(b * T_ + (tc0 + st)) * OUT_ + n] = oacc[r] + bo;
          }
        }
      }
    }

    // ===== boundary: batched ring stores + poll (overlapped) + publish + acquire =====
    if (ch + 1 < NCH) {
      if (l < L_ - 1) {  // whole super-chunk's h-tiles; drain overlaps tid0's poll
#pragma unroll
        for (int st = 0; st < CTT; ++st) {
          const u64 val = *(const u64*)(&hist[st][(tid >> 5) * LDSW_ + ((tid & 31) << 2)]);
          ring_st(&myring[(size_t)((tc0 + st) & (RING_T - 1)) * STEP_U64_ + tid], val);
        }
      }
      if (tid == 0) {
        if (RING_T < T_ && l > 0) flag_st(mycons, tc0 + CTT);  // BEFORE polls (no deadlock)
        if (l > 0) {
          const int target = tc0 + 2 * CTT;
          if (seen_prod < target) {
            int v;
            do { v = flag_ld(prevprod); } while (v < target);
            seen_prod = v;
          }
        }
        if (RING_T < T_ && l < L_ - 1 && tc0 + 2 * CTT > RING_T) {
          const int need = tc0 + 2 * CTT - RING_T;
          if (seen_cons < need) {
            int v;
            do { v = flag_ld(nextcons); } while (v < need);
            seen_cons = v;
          }
        }
      }
      __syncthreads();  // drains ring stores (per-wave vmcnt); gates polls
      if (l < L_ - 1 && tid == 0) {
        flag_st(myprod, tc0 + CTT);  // sc1 stores already at coherence point
      }
      if (l == 0) {
        const int m  = tid >> 5;
        const int c4 = (tid & 31) << 2;
#pragma unroll
        for (int tl = 0; tl < CTT; ++tl) {
          const int token = xids[(g * BG_ + m) * T_ + tc0 + CTT + tl];
          const float4 e = *(const float4*)(embed + token * H_ + c4);
          bf16x4 v;
          v[0] = (bf16_t)e.x; v[1] = (bf16_t)e.y; v[2] = (bf16_t)e.z; v[3] = (bf16_t)e.w;
          *(bf16x4*)(&xchunk[tl][m * LDSW_ + c4]) = v;
        }
      } else {
        const int idx = tid >> 2;
        if (idx < CTT * 16) {
          const int tl = idx >> 4, m = idx & 15, seg = tid & 3;
          const u64* src = srcring + (size_t)((tc0 + CTT + tl) & (RING_T - 1)) * STEP_U64_ + m * 32 + seg * 8;
          u64* dst = (u64*)(&xchunk[tl][m * LDSW_ + seg * 32]);
#pragma unroll
          for (int j = 0; j < 8; ++j) dst[j] = ring_ld(src + j);
        }
      }
      __syncthreads();  // xchunk(ch+1) ready
    } else if (l < L_ - 1) {
      // final chunk: batched stores, drain, publish T_
#pragma unroll
      for (int st = 0; st < CTT; ++st) {
        const u64 val = *(const u64*)(&hist[st][(tid >> 5) * LDSW_ + ((tid & 31) << 2)]);
        ring_st(&myring[(size_t)((tc0 + st) & (RING_T - 1)) * STEP_U64_ + tid], val);
      }
      __syncthreads();  // drain last chunk's ring stores
      if (tid == 0) {
        flag_st(myprod, T_);
      }
    }
  }
}

extern "C" void kernel_launch(void* const* d_in, const int* in_sizes, int n_in,
                              void* d_out, int out_size, void* d_ws, size_t ws_size,
                              hipStream_t stream) {
  (void)in_sizes; (void)n_in; (void)out_size;
  const int*   x     = (const int*)d_in[0];
  const float* embed = (const float*)d_in[1];
  const float* w_ih  = (const float*)d_in[2];
  const float* b_ih  = (const float*)d_in[3];
  const float* w_hh  = (const float*)d_in[4];
  const float* b_hh  = (const float*)d_in[5];
  const float* w_out = (const float*)d_in[6];
  const float* b_out = (const float*)d_in[7];
  float* out = (float*)d_out;

  int* flags = (int*)d_ws;                     // 8 KB: prod@0, cons@4KB
  u64* ring  = (u64*)((char*)d_ws + 8192);

  hipLaunchKernelGGL(zero_flags, dim3(2), dim3(1024), 0, stream, flags);

  auto need = [&](int ring_t) { return (size_t)8192 + (size_t)28 * ring_t * 4096; };

  if (ws_size >= need(512)) {        // 57 MB: full history, no back-pressure
    hipLaunchKernelGGL((lstm_pipe<4, 2, 512>), dim3(L_ * NG_), dim3(512), 0, stream,
                       x, embed, w_ih, b_ih, w_hh, b_hh, w_out, b_out, out, flags, ring);
  } else if (ws_size >= need(16)) {  // 1.8 MB
    hipLaunchKernelGGL((lstm_pipe<4, 2, 16>), dim3(L_ * NG_), dim3(512), 0, stream,
                       x, embed, w_ih, b_ih, w_hh, b_hh, w_out, b_out, out, flags, ring);
  } else if (ws_size >= need(8)) {   // 0.92 MB
    hipLaunchKernelGGL((lstm_pipe<4, 1, 8>), dim3(L_ * NG_), dim3(512), 0, stream,
                       x, embed, w_ih, b_ih, w_hh, b_hh, w_out, b_out, out, flags, ring);
  } else {                           // 0.47 MB worst case
    hipLaunchKernelGGL((lstm_pipe<2, 1, 4>), dim3(L_ * NG_), dim3(512), 0, stream,
                       x, embed, w_ih, b_ih, w_hh, b_hh, w_out, b_out, out, flags, ring);
  }
}